// Round 13
// baseline (7677.797 us; speedup 1.0000x reference)
//
#include <hip/hip_runtime.h>
#include <math.h>

using f16 = _Float16;
typedef __attribute__((ext_vector_type(8))) _Float16 f16x8;
typedef __attribute__((ext_vector_type(4))) _Float16 f16x4;
typedef __attribute__((ext_vector_type(4))) float f32x4;

#define T_STEPS 128
#define HID 400
#define G4 1600
#define XPLD 3200
#define HLD 416
#define WPAD 424
#define NSL 13
#define RNN_BLOCKS (NSL * 16)

__device__ __forceinline__ void gl_lds16(const void* g, void* l) {
  __builtin_amdgcn_global_load_lds((const __attribute__((address_space(1))) void*)g,
                                   (__attribute__((address_space(3))) void*)l, 16, 0, 0);
}

// cross-XCD-coherent ops: bypass L1+L2, hit the L3 coherence point
__device__ __forceinline__ f16x8 ld_cc(const f16* p) {
  f16x8 r;
  asm volatile("global_load_dwordx4 %0, %1, off sc0 sc1" : "=v"(r) : "v"(p));
  return r;  // caller must s_waitcnt vmcnt(0) + sched_barrier before use
}
__device__ __forceinline__ void st_cc2(f16* p, unsigned v) {
  asm volatile("global_store_short %0, %1, off sc0 sc1" :: "v"(p), "v"(v) : "memory");
}
__device__ __forceinline__ void st_cc4(unsigned* p, unsigned v) {
  asm volatile("global_store_dword %0, %1, off sc0 sc1" :: "v"(p), "v"(v) : "memory");
}
__device__ __forceinline__ unsigned ld_cc4(const unsigned* p) {
  unsigned v;
  asm volatile("global_load_dword %0, %1, off sc0 sc1\n\ts_waitcnt vmcnt(0)"
               : "=v"(v) : "v"(p) : "memory");
  return v;
}

// ---------------- conversion kernels ----------------
__global__ void k_cvt_f16(const float* __restrict__ s, f16* __restrict__ d, long long n) {
  long long i = ((long long)blockIdx.x * blockDim.x + threadIdx.x) * 4;
  long long stride = (long long)gridDim.x * blockDim.x * 4;
  for (; i < n; i += stride) {
    float4 v = *(const float4*)(s + i);
    f16x4 o = { (f16)v.x, (f16)v.y, (f16)v.z, (f16)v.w };
    *(f16x4*)(d + i) = o;
  }
}

// Wih f32 -> f16 with gate-interleave ROW permutation folded in:
// out row R = L*3200 + dirn*1600 + (j/16)*64 + (j%16)*4 + g  <-  in row (2L+dirn)*1600 + g*400 + j
__global__ void k_cvt_wih(const float* __restrict__ s, f16* __restrict__ d) {
  long long n4 = 9600LL * 200;  // 4 elems per iter
  for (long long i = (long long)blockIdx.x * blockDim.x + threadIdx.x; i < n4;
       i += (long long)gridDim.x * blockDim.x) {
    long long i4 = i * 4;
    int R = (int)(i4 / 800), c = (int)(i4 % 800);
    int L = R / 3200, rem = R % 3200;
    int dirn = rem / 1600, q = rem % 1600;
    int g = q & 3, jlo = (q >> 2) & 15, jhi = q >> 6;
    int inrow = (2 * L + dirn) * 1600 + g * HID + jhi * 16 + jlo;
    float4 v = *(const float4*)(s + (long long)inrow * 800 + c);
    f16x4 o = { (f16)v.x, (f16)v.y, (f16)v.z, (f16)v.w };
    *(f16x4*)(d + i4) = o;
  }
}

__global__ void k_cvt_whh(const float* __restrict__ s, f16* __restrict__ d, int nrows) {
  long long n = (long long)nrows * HLD;
  for (long long i = (long long)blockIdx.x * blockDim.x + threadIdx.x; i < n;
       i += (long long)gridDim.x * blockDim.x) {
    int row = (int)(i / HLD), c = (int)(i % HLD);
    d[i] = (c < HID) ? (f16)s[(long long)row * HID + c] : (f16)0.f;
  }
}

__global__ void k_bias(const float* __restrict__ a, const float* __restrict__ b,
                       float* __restrict__ d, int n) {
  for (int i = blockIdx.x * blockDim.x + threadIdx.x; i < n; i += gridDim.x * blockDim.x)
    d[i] = a[i] + b[i];
}

// ---------------- wave-local projection of a PAIR of steps ----------------
// Computes xproj tiles (16 rows x 128 gate-cols) for steps u0,u0+1 of this block's
// (dir,bt,slice). B streams from L2 (permuted-Wih slab); no LDS, no barriers.
__device__ __forceinline__ void project_pair(
    const f16* __restrict__ A, int lda, int nkp, const f16* __restrict__ wp,
    f16* __restrict__ xq, const int* bsT, const int* offT,
    int u0p, int dir, int btrows, int rowb, int lane) {
  const int lr = lane & 15, kreg = (lane >> 4) * 8, qr4 = (lane >> 4) * 4;
  const int u1p = u0p + 1;
  const int t0 = dir ? (T_STEPS - 1 - u0p) : u0p;
  const int t1 = dir ? (T_STEPS - 1 - u1p) : u1p;
  const bool a0v = (u0p < T_STEPS) && (bsT[t0] > btrows);
  const bool a1v = (u1p < T_STEPS) && (bsT[t1] > btrows);
  if (!a0v && !a1v) return;
  const size_t r0 = a0v ? (size_t)(offT[t0] + rowb) : 0;
  const size_t r1 = a1v ? (size_t)(offT[t1] + rowb) : 0;
  f32x4 p0[8] = {}, p1[8] = {};
  for (int kc = 0; kc < nkp; ++kc) {
    const int k0 = kc * 32;
    f16x8 a0 = {}, a1 = {};
    if (a0v) a0 = *(const f16x8*)&A[(r0 + lr) * (size_t)lda + k0 + kreg];
    if (a1v) a1 = *(const f16x8*)&A[(r1 + lr) * (size_t)lda + k0 + kreg];
#pragma unroll
    for (int nt = 0; nt < 8; ++nt) {
      f16x8 b8 = *(const f16x8*)&wp[(nt * 16 + lr) * 800 + k0 + kreg];
      if (a0v) p0[nt] = __builtin_amdgcn_mfma_f32_16x16x32_f16(a0, b8, p0[nt], 0, 0, 0);
      if (a1v) p1[nt] = __builtin_amdgcn_mfma_f32_16x16x32_f16(a1, b8, p1[nt], 0, 0, 0);
    }
  }
#pragma unroll
  for (int nt = 0; nt < 8; ++nt)
#pragma unroll
    for (int r = 0; r < 4; ++r) {
      int b = rowb + qr4 + r;
      if (a0v && b < bsT[t0]) xq[(size_t)(offT[t0] + b) * XPLD + nt * 16 + lr] = (f16)p0[nt][r];
      if (a1v && b < bsT[t1]) xq[(size_t)(offT[t1] + b) * XPLD + nt * 16 + lr] = (f16)p1[nt][r];
    }
}

// ---------------- FUSED persistent recurrence + projection ----------------
// 208 blocks (13 slices x 16 groups), 512 thr = 8 waves; wave w owns rows
// [bt*128+w*16,+16) x 32 j-cols. Whh slice in LDS; projection of x@Wih^T for
// future steps runs in look-ahead batches during sync idle time (wave-local).
__global__ __launch_bounds__(512) void k_rnnf(
    f16* __restrict__ xp,             // xproj workspace (written & read by self)
    const f16* __restrict__ A,        // layer input (x16 / layA / layB)
    int lda, int nkp,                 // A row stride, K/32 for projection
    const f16* __restrict__ wihP,     // permuted Wih layer base (rows x 800)
    const f16* __restrict__ whh, const float* __restrict__ bias2,
    f16* __restrict__ h16, float* __restrict__ hn, float* __restrict__ cn,
    f16* __restrict__ outf16, float* __restrict__ outf32,
    unsigned* __restrict__ flags) {
  __shared__ f16 Wl[128 * WPAD];  // 4 gates x 32 j rows, 416(+8) cols
  __shared__ int bsT[T_STEPS], offT[T_STEPS];

  const int tid = threadIdx.x;
  const int slice = blockIdx.x % NSL;
  const int q = blockIdx.x / NSL;  // dir*8 + bt
  const int dir = q >> 3, bt = q & 7;
  const int lane = tid & 63, w = tid >> 6;
  const int lr = lane & 15, kreg = (lane >> 4) * 8;
  const int qr4 = (lane >> 4) * 4;
  const int j0 = slice * 32;
  unsigned* line = flags + ((size_t)q * 8 + w) * 32;
  const unsigned* peer = line + (lane < NSL ? lane : 0);

  if (tid == 0) {
    double step = (1.0 - 1024.0) / 127.0;
    for (int i = 0; i < T_STEPS; ++i) bsT[i] = (int)floor((double)i * step + 1024.0);
    bsT[127] = 1; bsT[0] = 1024;
    int sum = 0;
    for (int i = 0; i < T_STEPS; ++i) sum += bsT[i];
    int diff = 65536 - sum;
    while (diff != 0) {
      if (diff > 0) {
        for (int jj = 1; jj < T_STEPS && diff != 0; ++jj) {
          int cap = bsT[jj - 1] - bsT[jj];
          int add = cap < diff ? cap : diff;
          bsT[jj] += add; diff -= add;
        }
      } else {
        for (int jj = T_STEPS - 1; jj >= 1 && diff != 0; --jj) {
          int nxt = (jj + 1 < T_STEPS) ? bsT[jj + 1] : 1;
          int room = bsT[jj] - nxt;
          int sub = room < (-diff) ? room : (-diff);
          bsT[jj] -= sub; diff += sub;
        }
      }
    }
    int a0 = 0;
    for (int i = 0; i < T_STEPS; ++i) { offT[i] = a0; a0 += bsT[i]; }
  }

  // Whh slice -> LDS: 128 rows (4 gates x 32 j), 416 cols (pad stride 424)
  const f16* whhD = whh + (size_t)dir * (G4 * HLD);
  {
    int rr = tid >> 2, seg = tid & 3;
    int g = rr >> 5, jsub = rr & 31;
    const f16* src = whhD + (size_t)(g * HID + j0 + jsub) * HLD + seg * 104;
    f16* dst = &Wl[rr * WPAD + seg * 104];
#pragma unroll
    for (int kk = 0; kk < 13; ++kk)
      *(f16x8*)(dst + kk * 8) = *(const f16x8*)(src + kk * 8);
  }
  const float* biD = bias2 + dir * G4;
  float bi[2][4];
#pragma unroll
  for (int h = 0; h < 2; ++h) {
    int jc = j0 + h * 16 + lr;
#pragma unroll
    for (int g = 0; g < 4; ++g)
      bi[h][g] = (jc < HID) ? biD[g * HID + jc] : 0.f;
  }
  float* hp = hn + (size_t)dir * (1024 * HID);
  float* cp = cn + (size_t)dir * (1024 * HID);
  __syncthreads();  // W + tables ready

  int s_begin = 0;
  if (dir) {
    while (s_begin < T_STEPS && bsT[T_STEPS - 1 - s_begin] <= bt * 128) ++s_begin;
  }
  const int rowb = bt * 128 + w * 16;
  const int btrows = bt * 128;
  float ch[2][4] = {};

  // projection setup: this block's Wih slab + xproj column base
  const f16* wp = wihP + (size_t)(dir * G4 + slice * 128) * 800;
  f16* xq = xp + dir * G4 + slice * 128;

  // prologue: project first 16 steps' rows
  int nu = s_begin;
#pragma unroll 1
  for (int pb = 0; pb < 8; ++pb) {
    project_pair(A, lda, nkp, wp, xq, bsT, offT, nu, dir, btrows, rowb, lane);
    nu += 2;
  }

  // initial x prefetch (step s_begin)
  f16x4 xgA[2][4], xgB[2][4];
  {
    int tt = dir ? (T_STEPS - 1 - s_begin) : s_begin;
    int bs0 = bsT[tt], off0 = offT[tt];
#pragma unroll
    for (int r = 0; r < 4; ++r) {
      int b = rowb + qr4 + r;
      if (b < bs0) {
        const f16* xr = xp + (size_t)(off0 + b) * XPLD + dir * G4 + slice * 128 + lr * 4;
        xgA[0][r] = *(const f16x4*)(xr);
        xgA[1][r] = *(const f16x4*)(xr + 64);
      }
    }
  }

#pragma unroll 1
  for (int s = s_begin; s < T_STEPS; ++s) {
    const int t = dir ? (T_STEPS - 1 - s) : s;
    const int bs = bsT[t], off = offT[t];
    const bool lastStep = (s == T_STEPS - 1) || (!dir && bsT[s + 1] <= btrows);

    // look-ahead projection batch (wave-local; runs in sync-idle shadow)
    if (nu < T_STEPS && nu < s + 10) {
#pragma unroll 1
      for (int pb = 0; pb < 4; ++pb) {
        project_pair(A, lda, nkp, wp, xq, bsT, offT, nu, dir, btrows, rowb, lane);
        nu += 2;
      }
    }

    // prefetch NEXT step's x (2-deep; guarded by next bs)
    if (!lastStep) {
      int tn = dir ? (T_STEPS - 2 - s) : (s + 1);
      int bsn = bsT[tn], offn = offT[tn];
#pragma unroll
      for (int r = 0; r < 4; ++r) {
        int b = rowb + qr4 + r;
        if (b < bsn) {
          const f16* xr = xp + (size_t)(offn + b) * XPLD + dir * G4 + slice * 128 + lr * 4;
          xgB[0][r] = *(const f16x4*)(xr);
          xgB[1][r] = *(const f16x4*)(xr + 64);
        }
      }
    }

    // wait: same-index waves of all 13 slices done step s-1 (one-line poll)
    if (s > s_begin) {
      while (true) {
        unsigned vv = ld_cc4(peer);
        if (!__ballot((lane < NSL) && (vv < (unsigned)s))) break;
        __builtin_amdgcn_s_sleep(1);
      }
    }

    const int cur = s & 1;
    const f16* hr = h16 + (size_t)((dir << 1) | cur) * (1024 * HLD);
    f16* hww = h16 + (size_t)((dir << 1) | (cur ^ 1)) * (1024 * HLD);

    const f16* ha = hr + (size_t)(rowb + lr) * HLD + kreg;
    f16x8 hf[13];
#pragma unroll
    for (int kk = 0; kk < 13; ++kk) hf[kk] = ld_cc(ha + kk * 32);
    asm volatile("s_waitcnt vmcnt(0)" ::: "memory");
    __builtin_amdgcn_sched_barrier(0);

    __builtin_amdgcn_s_setprio(1);
    f32x4 acc[8] = {};  // [g*2+h]
#pragma unroll
    for (int kk = 0; kk < 13; ++kk) {
#pragma unroll
      for (int nt = 0; nt < 8; ++nt) {
        f16x8 bf = *(const f16x8*)&Wl[(((nt >> 1) << 5) + ((nt & 1) << 4) + lr) * WPAD
                                      + kk * 32 + kreg];
        acc[nt] = __builtin_amdgcn_mfma_f32_16x16x32_f16(hf[kk], bf, acc[nt], 0, 0, 0);
      }
    }
    __builtin_amdgcn_s_setprio(0);

    float hnw[2][4];
    f16 hv16[2][4];
#pragma unroll
    for (int h = 0; h < 2; ++h) {
      const int jc = j0 + h * 16 + lr;
#pragma unroll
      for (int r = 0; r < 4; ++r) {
        int b = rowb + qr4 + r;
        if (b < bs && jc < HID) {  // pad-j cells never stored -> h pad stays 0
          float Gi = acc[0 + h][r] + (float)xgA[h][r][0] + bi[h][0];
          float Gf = acc[2 + h][r] + (float)xgA[h][r][1] + bi[h][1];
          float Gg = acc[4 + h][r] + (float)xgA[h][r][2] + bi[h][2];
          float Go = acc[6 + h][r] + (float)xgA[h][r][3] + bi[h][3];
          float ii = 1.f / (1.f + __expf(-Gi));
          float ff = 1.f / (1.f + __expf(-Gf));
          float gg = 1.f - 2.f / (__expf(2.f * Gg) + 1.f);
          float oo = 1.f / (1.f + __expf(-Go));
          float cnew = ff * ch[h][r] + ii * gg;
          ch[h][r] = cnew;
          float hnew = oo * (1.f - 2.f / (__expf(2.f * cnew) + 1.f));
          union { f16 f; unsigned short u; } cv; cv.f = (f16)hnew;
          st_cc2(&hww[(size_t)b * HLD + jc], (unsigned)cv.u);
          hnw[h][r] = hnew;
          hv16[h][r] = cv.f;
        }
      }
    }

    if (!lastStep) {
      asm volatile("s_waitcnt vmcnt(0)" ::: "memory");  // wave's h ACKed at L3
      if (lane == 0) st_cc4((unsigned*)(line + slice), (unsigned)(s + 1));
    }

    // deferred outputs (overlap next step's prefetch/spin)
#pragma unroll
    for (int h = 0; h < 2; ++h) {
      const int jc = j0 + h * 16 + lr;
#pragma unroll
      for (int r = 0; r < 4; ++r) {
        int b = rowb + qr4 + r;
        if (b < bs && jc < HID) {
          size_t prow = (size_t)(off + b);
          if (outf32) outf32[prow * 800 + dir * HID + jc] = hnw[h][r];
          else        outf16[prow * 800 + dir * HID + jc] = hv16[h][r];
          bool lastv = dir ? (s == T_STEPS - 1)
                           : (s == T_STEPS - 1 || bsT[s + 1] <= b);
          if (lastv) {
            cp[(size_t)b * HID + jc] = ch[h][r];
            hp[(size_t)b * HID + jc] = hnw[h][r];
          }
        }
      }
    }
    if (lastStep) break;
#pragma unroll
    for (int h = 0; h < 2; ++h)
#pragma unroll
      for (int r = 0; r < 4; ++r) xgA[h][r] = xgB[h][r];
  }
}

// ---------------- fallback: staged GEMM (256x128, 3-buf T4) ----------------
__global__ __launch_bounds__(512) void k_gemm(const f16* __restrict__ A,
                                              const f16* __restrict__ Bw,
                                              f16* __restrict__ C, int lda, int K) {
  __shared__ f16 As[3][256 * 32];
  __shared__ f16 Bs[3][128 * 32];
  const int tid = threadIdx.x;
  const int lane = tid & 63, v = tid >> 6;
  const int wm = v >> 1, wn = v & 1;
  const int wg = blockIdx.x;
  const int swz = (wg & 7) * 800 + (wg >> 3);
  const int bn = (swz % 25) * 128;
  const long long bm = (long long)(swz / 25) * 256;

  const int kc = ((lane & 3) ^ ((lane >> 3) & 3)) * 8;
  const int srow = (v * 64 + lane) >> 2;
  const f16* gA0 = A + (bm + srow) * (long long)lda + kc;
  const f16* gA1 = A + (bm + 128 + srow) * (long long)lda + kc;
  const f16* gB0 = Bw + (long long)(bn + srow) * 800 + kc;

  const int lr = lane & 15;
  const int kswz = (((lane >> 4) ^ ((lr >> 1) & 3)) << 3);
  const int nk = K / 32;

  f32x4 acc[4][4] = {};

#define STAGE(bb, k0)                              \
  do {                                             \
    gl_lds16(gA0 + (k0), &As[bb][v * 512]);        \
    gl_lds16(gA1 + (k0), &As[bb][4096 + v * 512]); \
    gl_lds16(gB0 + (k0), &Bs[bb][v * 512]);        \
  } while (0)

  STAGE(0, 0);
  STAGE(1, 32);
  int cur = 0;
  for (int kt = 0; kt < nk; ++kt) {
    if (kt + 1 < nk) asm volatile("s_waitcnt vmcnt(3)" ::: "memory");
    else             asm volatile("s_waitcnt vmcnt(0)" ::: "memory");
    __builtin_amdgcn_s_barrier();
    f16x8 af[4], bf[4];
#pragma unroll
    for (int mt = 0; mt < 4; ++mt)
      af[mt] = *(const f16x8*)&As[cur][(wm * 64 + mt * 16 + lr) * 32 + kswz];
#pragma unroll
    for (int nt = 0; nt < 4; ++nt)
      bf[nt] = *(const f16x8*)&Bs[cur][(wn * 64 + nt * 16 + lr) * 32 + kswz];
    if (kt + 2 < nk) {
      int nb = cur + 2; if (nb >= 3) nb -= 3;
      STAGE(nb, (kt + 2) * 32);
    }
#pragma unroll
    for (int mt = 0; mt < 4; ++mt)
#pragma unroll
      for (int nt = 0; nt < 4; ++nt)
        acc[mt][nt] = __builtin_amdgcn_mfma_f32_16x16x32_f16(af[mt], bf[nt], acc[mt][nt], 0, 0, 0);
    ++cur; if (cur >= 3) cur -= 3;
  }
#undef STAGE

#pragma unroll
  for (int mt = 0; mt < 4; ++mt) {
#pragma unroll
    for (int nt = 0; nt < 4; ++nt) {
      long long gm = bm + wm * 64 + mt * 16 + ((lane >> 4) * 4);
      int gn = bn + wn * 64 + nt * 16 + lr;
#pragma unroll
      for (int r = 0; r < 4; ++r)
        C[(gm + r) * XPLD + gn] = (f16)acc[mt][nt][r];
    }
  }
}

// ---------------- fallback per-step kernel ----------------
__global__ __launch_bounds__(256) void k_step(
    const f16* __restrict__ xp, const f16* __restrict__ whh,
    const float* __restrict__ bias2, const f16* __restrict__ h16r0,
    f16* __restrict__ h16w0, float* __restrict__ hn, float* __restrict__ cn,
    f16* __restrict__ outf16, float* __restrict__ outf32,
    int bs_f, int off_f, int bs_b, int off_b, int nTf) {
  const int slice = blockIdx.x % 25;
  const int tl = blockIdx.x / 25;
  int dir, bt, bs, off;
  if (tl < nTf) { dir = 0; bt = tl; bs = bs_f; off = off_f; }
  else          { dir = 1; bt = tl - nTf; bs = bs_b; off = off_b; }
  const int lane = threadIdx.x & 63, w = threadIdx.x >> 6;
  const int lr = lane & 15, kreg = (lane >> 4) * 8;
  const int b0 = bt * 128;
  const int j0 = slice * 16;
  const f16* hr = h16r0 + (size_t)dir * (2 * 1024 * HLD);
  f16* hw = h16w0 + (size_t)dir * (2 * 1024 * HLD);
  const f16* W = whh + (size_t)dir * (G4 * HLD);
  const float* bi = bias2 + dir * G4;
  float* hp = hn + (size_t)dir * (1024 * HID);
  float* cp = cn + (size_t)dir * (1024 * HID);

  f32x4 acc[2][4] = {};
  for (int k0 = 0; k0 < HLD; k0 += 32) {
    f16x8 af0 = *(const f16x8*)&hr[(b0 + (w * 2 + 0) * 16 + lr) * HLD + k0 + kreg];
    f16x8 af1 = *(const f16x8*)&hr[(b0 + (w * 2 + 1) * 16 + lr) * HLD + k0 + kreg];
#pragma unroll
    for (int g = 0; g < 4; ++g) {
      f16x8 bf = *(const f16x8*)&W[(g * HID + j0 + lr) * HLD + k0 + kreg];
      acc[0][g] = __builtin_amdgcn_mfma_f32_16x16x32_f16(af0, bf, acc[0][g], 0, 0, 0);
      acc[1][g] = __builtin_amdgcn_mfma_f32_16x16x32_f16(af1, bf, acc[1][g], 0, 0, 0);
    }
  }
  const int j = j0 + lr;
#pragma unroll
  for (int mt = 0; mt < 2; ++mt) {
#pragma unroll
    for (int r = 0; r < 4; ++r) {
      int b = b0 + (w * 2 + mt) * 16 + (lane >> 4) * 4 + r;
      if (b < bs) {
        size_t prow = (size_t)(off + b);
        const f16* xr = xp + prow * XPLD + dir * G4 + slice * 64 + lr * 4;
        float Gi = acc[mt][0][r] + (float)xr[0] + bi[j];
        float Gf = acc[mt][1][r] + (float)xr[1] + bi[HID + j];
        float Gg = acc[mt][2][r] + (float)xr[2] + bi[2 * HID + j];
        float Go = acc[mt][3][r] + (float)xr[3] + bi[3 * HID + j];
        float ii = 1.f / (1.f + __expf(-Gi));
        float ff = 1.f / (1.f + __expf(-Gf));
        float gg = 1.f - 2.f / (__expf(2.f * Gg) + 1.f);
        float oo = 1.f / (1.f + __expf(-Go));
        float co = cp[b * HID + j];
        float cnew = ff * co + ii * gg;
        float hnew = oo * (1.f - 2.f / (__expf(2.f * cnew) + 1.f));
        cp[b * HID + j] = cnew;
        hp[b * HID + j] = hnew;
        hw[b * HLD + j] = (f16)hnew;
        if (outf32) outf32[prow * 800 + dir * HID + j] = hnew;
        else        outf16[prow * 800 + dir * HID + j] = (f16)hnew;
      }
    }
  }
}

// ---------------- host ----------------
extern "C" void kernel_launch(void* const* d_in, const int* in_sizes, int n_in,
                              void* d_out, int out_size, void* d_ws, size_t ws_size,
                              hipStream_t stream) {
  (void)in_sizes; (void)n_in; (void)out_size; (void)ws_size;
  const float* x   = (const float*)d_in[0];
  const float* Wih = (const float*)d_in[1];
  const float* Whh = (const float*)d_in[2];
  const float* bih = (const float*)d_in[3];
  const float* bhh = (const float*)d_in[4];
  float* out = (float*)d_out;

  long long bsv[128];
  {
    double step = (1.0 - 1024.0) / 127.0;
    for (int i = 0; i < 128; ++i) bsv[i] = (long long)floor((double)i * step + 1024.0);
    bsv[127] = 1; bsv[0] = 1024;
    long long sum = 0;
    for (int i = 0; i < 128; ++i) sum += bsv[i];
    long long diff = 65536 - sum;
    while (diff != 0) {
      if (diff > 0) {
        for (int jj = 1; jj < 128 && diff != 0; ++jj) {
          long long cap = bsv[jj - 1] - bsv[jj];
          long long add = cap < diff ? cap : diff;
          bsv[jj] += add; diff -= add;
        }
      } else {
        for (int jj = 127; jj >= 1 && diff != 0; --jj) {
          long long nxt = (jj + 1 < 128) ? bsv[jj + 1] : 1;
          long long room = bsv[jj] - nxt;
          long long sub = room < (-diff) ? room : (-diff);
          bsv[jj] -= sub; diff += sub;
        }
      }
    }
  }
  long long offv[128], a0 = 0;
  for (int i = 0; i < 128; ++i) { offv[i] = a0; a0 += bsv[i]; }

  char* p = (char*)d_ws;
  f16*      x16   = (f16*)(p);                 // 65536x400 f16 (+256B zero pad)
  f16*      wih16 = (f16*)(p + 52429056LL);    // 6x1600x800 f16, gate-permuted rows
  f16*      whh16 = (f16*)(p + 67789056LL);    // 6x1600x416 f16 (zero-padded K)
  float*    bias  = (float*)(p + 75776256LL);  // 6x1600 f32
  f16*      xproj = (f16*)(p + 75814656LL);    // (65536+128)x3200 f16
  unsigned* flags = (unsigned*)(p + 495654656LL);  // 3 layers x 16 groups x 8 waves x 128B
  f16*      layA  = (f16*)(p + 496064256LL);   // 65536x800 f16
  f16*      layB  = (f16*)(p + 600921856LL);   // 65536x800 f16
  f16*      h16   = (f16*)(p + 705779456LL);   // 2 dir x 2 pp x 1024x416 f16

  hipMemsetAsync(p + 52428800LL, 0, 256, stream);              // x16 K-pad
  hipMemsetAsync(out + 52428800LL, 0, 4915200LL * 4, stream);  // h_n + c_n
  hipMemsetAsync(flags, 0, 3 * 16 * 8 * 128, stream);          // all layer flags

  k_cvt_f16<<<2048, 256, 0, stream>>>(x, x16, 26214400LL);
  k_cvt_wih<<<2048, 256, 0, stream>>>(Wih, wih16);
  k_cvt_whh<<<2048, 256, 0, stream>>>(Whh, whh16, 9600);
  k_bias<<<40, 256, 0, stream>>>(bih, bhh, bias, 9600);

  int occ = 0;
  hipOccupancyMaxActiveBlocksPerMultiprocessor(&occ, k_rnnf, 512, 0);
  const bool persistent = (occ >= 1);  // 208 blocks <= 256 CUs at 1/CU

  const long long OUTP = 52428800LL, HNSZ = 2457600LL;

  for (int L = 0; L < 3; ++L) {
    const f16* Ain = (L == 0) ? x16 : (L == 1 ? layA : layB);
    int lda = (L == 0) ? 400 : 800;
    int K   = (L == 0) ? 416 : 800;
    hipMemsetAsync(h16, 0, 3407872LL, stream);
    float* hnL = out + OUTP + (size_t)(2 * L) * 409600;
    float* cnL = out + OUTP + HNSZ + (size_t)(2 * L) * 409600;
    f16* o16 = (L == 0) ? layA : (L == 1 ? layB : nullptr);
    float* o32 = (L == 2) ? out : nullptr;
    if (persistent) {
      k_rnnf<<<RNN_BLOCKS, 512, 0, stream>>>(
          xproj, Ain, lda, K / 32, wih16 + (size_t)L * 3200 * 800,
          whh16 + (size_t)(2 * L) * 1600 * HLD, bias + (size_t)(2 * L) * 1600,
          h16, hnL, cnL, o16, o32, flags + (size_t)L * 16 * 8 * 32);
    } else {
      k_gemm<<<6400, 512, 0, stream>>>(Ain, wih16 + (size_t)(2 * L) * 1600 * 800,
                                       xproj, lda, K);
      for (int s = 0; s < 128; ++s) {
        int tf = s, tb = 127 - s;
        int bsf = (int)bsv[tf], bsb = (int)bsv[tb];
        int nTf = (bsf + 127) / 128, nTb = (bsb + 127) / 128;
        k_step<<<25 * (nTf + nTb), 256, 0, stream>>>(
            xproj, whh16 + (size_t)(2 * L) * 1600 * HLD, bias + (size_t)(2 * L) * 1600,
            h16 + (size_t)(s & 1) * 1024 * HLD, h16 + (size_t)((s + 1) & 1) * 1024 * HLD,
            hnL, cnL, o16, o32,
            bsf, (int)offv[tf], bsb, (int)offv[tb], nTf);
      }
    }
  }
}